// Round 1
// baseline (1069.845 us; speedup 1.0000x reference)
//
#include <hip/hip_runtime.h>

#define EPS 1e-05f
#define ALPHA 0.05f

__device__ __forceinline__ float rcp_f(float x){ return __builtin_amdgcn_rcpf(x); }

#define LOG2E 1.4426950408889634f
#define LN2   0.6931471805599453f

// tanh(x) = sign(x) * (1 - e) / (1 + e),  e = exp(-2|x|)
__device__ __forceinline__ float fast_tanh(float x){
  float ax = fabsf(x);
  float e  = exp2f(ax * (-2.0f * LOG2E));
  float t  = (1.0f - e) * rcp_f(1.0f + e);
  return copysignf(t, x);
}
// softplus(x) = max(x,0) + log1p(exp(-|x|))
__device__ __forceinline__ float fast_sp(float x){
  float ax = fabsf(x);
  float e  = exp2f(ax * -LOG2E);
  return fmaxf(x, 0.0f) + log2f(1.0f + e) * LN2;
}
// sigmoid(x)
__device__ __forceinline__ float fast_sig(float x){
  float ax = fabsf(x);
  float e  = exp2f(ax * -LOG2E);
  float r  = rcp_f(1.0f + e);
  return x >= 0.0f ? r : e * r;
}
// sigmoid(z) given sp = softplus(z):  sig = 1 - exp(-sp)
__device__ __forceinline__ float sig_from_sp(float sp){
  return 1.0f - exp2f(sp * -LOG2E);
}

// ---------------- yref = icnn(xref) (one tiny block) ----------------
__global__ void holo_yref(const float* __restrict__ xref,
    const float* __restrict__ iw1, const float* __restrict__ ib1,
    const float* __restrict__ iw2, const float* __restrict__ ib2,
    const float* __restrict__ iw3, const float* __restrict__ ib3,
    const float* __restrict__ iw4, const float* __restrict__ ib4,
    const float* __restrict__ im2, const float* __restrict__ im3,
    const float* __restrict__ im4, float* __restrict__ ws)
{
  __shared__ float s1[60], s2[60], s3[30];
  int t = threadIdx.x;
  float xr[6];
  for (int k = 0; k < 6; k++) xr[k] = xref[k];
  if (t < 60){
    float z = ib1[t];
    for (int k = 0; k < 6; k++) z = fmaf(iw1[t*6+k], xr[k], z);
    s1[t] = fast_sp(z);
  }
  __syncthreads();
  if (t < 60){
    float z = ib2[t];
    for (int k = 0; k < 6; k++) z = fmaf(im2[t*6+k], xr[k], z);
    for (int j = 0; j < 60; j++) z = fmaf(iw2[t*60+j], s1[j], z);
    s2[t] = fast_sp(z);
  }
  __syncthreads();
  if (t < 30){
    float z = ib3[t];
    for (int k = 0; k < 6; k++) z = fmaf(im3[t*6+k], xr[k], z);
    for (int j = 0; j < 60; j++) z = fmaf(iw3[t*60+j], s2[j], z);
    s3[t] = fast_sp(z);
  }
  __syncthreads();
  if (t == 0){
    float y = ib4[0];
    for (int k = 0; k < 6; k++) y = fmaf(im4[k], xr[k], y);
    for (int j = 0; j < 30; j++) y = fmaf(iw4[j], s3[j], y);
    ws[0] = y;
  }
}

// ---------------- main: one thread per sample ----------------
__global__ __launch_bounds__(256) void holo_main(
    const float* __restrict__ X, const float* __restrict__ U,
    const float* __restrict__ xref,
    const float* __restrict__ fw1, const float* __restrict__ fb1,
    const float* __restrict__ fw2, const float* __restrict__ fb2,
    const float* __restrict__ fw3, const float* __restrict__ fb3,
    const float* __restrict__ gw,  const float* __restrict__ gb,
    const float* __restrict__ iw1, const float* __restrict__ ib1,
    const float* __restrict__ iw2, const float* __restrict__ ib2,
    const float* __restrict__ iw3, const float* __restrict__ ib3,
    const float* __restrict__ iw4, const float* __restrict__ ib4,
    const float* __restrict__ im2, const float* __restrict__ im3,
    const float* __restrict__ im4,
    const float* __restrict__ yref_ws,
    float* __restrict__ out, int N)
{
  int i = blockIdx.x * blockDim.x + threadIdx.x;
  if (i >= N) return;

  float x[6];
  #pragma unroll
  for (int k = 0; k < 6; k++) x[k] = X[(long)i*6 + k];

  // ================= FNN: 6 -> 80 -> 200 -> 6 =================
  float h1[80];
  #pragma unroll
  for (int o = 0; o < 80; o++){
    float z = fb1[o];
    #pragma unroll
    for (int k = 0; k < 6; k++) z = fmaf(fw1[o*6+k], x[k], z);
    h1[o] = fast_tanh(z);
  }
  float f[6];
  #pragma unroll
  for (int d = 0; d < 6; d++) f[d] = fb3[d];
  for (int j = 0; j < 200; j += 4){           // rolled: uniform weight idx -> s_load
    float z0 = fb2[j+0], z1 = fb2[j+1], z2 = fb2[j+2], z3 = fb2[j+3];
    #pragma unroll
    for (int k = 0; k < 80; k++){
      float h = h1[k];
      z0 = fmaf(fw2[(j+0)*80+k], h, z0);
      z1 = fmaf(fw2[(j+1)*80+k], h, z1);
      z2 = fmaf(fw2[(j+2)*80+k], h, z2);
      z3 = fmaf(fw2[(j+3)*80+k], h, z3);
    }
    z0 = fast_tanh(z0); z1 = fast_tanh(z1); z2 = fast_tanh(z2); z3 = fast_tanh(z3);
    #pragma unroll
    for (int d = 0; d < 6; d++){
      float fd = f[d];
      fd = fmaf(fw3[d*200+j+0], z0, fd);
      fd = fmaf(fw3[d*200+j+1], z1, fd);
      fd = fmaf(fw3[d*200+j+2], z2, fd);
      fd = fmaf(fw3[d*200+j+3], z3, fd);
      f[d] = fd;
    }
  }

  // ================= ICNN forward =================
  // c2 = b2 + Im2 x
  float c2[60];
  #pragma unroll
  for (int j = 0; j < 60; j++){
    float z = ib2[j];
    #pragma unroll
    for (int k = 0; k < 6; k++) z = fmaf(im2[j*6+k], x[k], z);
    c2[j] = z;
  }
  // c2 += W2 * softplus(z1), streaming z1 (z1 recomputed later for bwd)
  for (int k1 = 0; k1 < 60; k1++){
    float z = ib1[k1];
    #pragma unroll
    for (int k = 0; k < 6; k++) z = fmaf(iw1[k1*6+k], x[k], z);
    float s = fast_sp(z);
    #pragma unroll
    for (int j = 0; j < 60; j++) c2[j] = fmaf(iw2[j*60+k1], s, c2[j]);
  }
  // c2 := softplus(z2)   (sigmoid recoverable via 1-exp(-sp))
  #pragma unroll
  for (int j = 0; j < 60; j++) c2[j] = fast_sp(c2[j]);

  // layer3 fwd + y + g3 + Im3^T g3
  float y = ib4[0];
  #pragma unroll
  for (int k = 0; k < 6; k++) y = fmaf(im4[k], x[k], y);
  float ac[6];
  #pragma unroll
  for (int d = 0; d < 6; d++) ac[d] = im4[d];
  float g3[30];
  #pragma unroll
  for (int i3 = 0; i3 < 30; i3++){
    float z = ib3[i3];
    #pragma unroll
    for (int k = 0; k < 6; k++) z = fmaf(im3[i3*6+k], x[k], z);
    #pragma unroll
    for (int j = 0; j < 60; j++) z = fmaf(iw3[i3*60+j], c2[j], z);
    float sp3 = fast_sp(z);
    y = fmaf(iw4[i3], sp3, y);
    float gi = iw4[i3] * fast_sig(z);
    g3[i3] = gi;
    #pragma unroll
    for (int d = 0; d < 6; d++) ac[d] = fmaf(gi, im3[i3*6+d], ac[d]);
  }

  // g2 = sig(z2) .* (W3^T g3);  ac += Im2^T g2
  #pragma unroll
  for (int j = 0; j < 60; j++){
    float t = 0.0f;
    #pragma unroll
    for (int i3 = 0; i3 < 30; i3++) t = fmaf(iw3[i3*60+j], g3[i3], t);
    t *= sig_from_sp(c2[j]);
    #pragma unroll
    for (int d = 0; d < 6; d++) ac[d] = fmaf(t, im2[j*6+d], ac[d]);
    c2[j] = t;    // c2 now holds g2
  }
  // g1 = sig(z1) .* (W2^T g2);  ac += W1^T g1   (z1 recomputed)
  for (int k1 = 0; k1 < 60; k1++){
    float z = ib1[k1];
    #pragma unroll
    for (int k = 0; k < 6; k++) z = fmaf(iw1[k1*6+k], x[k], z);
    float t = 0.0f;
    #pragma unroll
    for (int j = 0; j < 60; j++) t = fmaf(iw2[j*60+k1], c2[j], t);
    t *= fast_sig(z);
    #pragma unroll
    for (int d = 0; d < 6; d++) ac[d] = fmaf(t, iw1[k1*6+d], ac[d]);
  }

  // ================= V, dV =================
  float yref = yref_ws[0];
  float h = y - yref;
  float sigma = (h >= 1.0f) ? (h - 0.5f) : ((h > 0.0f) ? 0.5f*h*h : 0.0f);
  float sigp  = (h >= 1.0f) ? 1.0f       : ((h > 0.0f) ? h        : 0.0f);
  float dx2 = 0.0f;
  float dV[6];
  #pragma unroll
  for (int d = 0; d < 6; d++){
    float dx = x[d] - xref[d];
    dx2 = fmaf(dx, dx, dx2);
    dV[d] = fmaf(sigp, ac[d], 2.0f*EPS*dx);
  }
  float V = sigma + EPS*dx2;

  float sc = ALPHA * V;
  #pragma unroll
  for (int d = 0; d < 6; d++) sc = fmaf(dV[d], f[d], sc);

  // ================= GNN + combine =================
  float u[6];
  #pragma unroll
  for (int m = 0; m < 6; m++) u[m] = U[(long)i*6 + m];
  float am[6] = {0.f,0.f,0.f,0.f,0.f,0.f};
  float gU[6];
  #pragma unroll
  for (int d = 0; d < 6; d++){
    float acc = 0.0f;
    #pragma unroll
    for (int m = 0; m < 6; m++){
      int o = d*6 + m;
      float g = gb[o];
      #pragma unroll
      for (int k = 0; k < 6; k++) g = fmaf(gw[o*6+k], x[k], g);
      am[m] = fmaf(dV[d], g, am[m]);
      acc   = fmaf(g, u[m], acc);
    }
    gU[d] = acc;
  }
  #pragma unroll
  for (int m = 0; m < 6; m++) sc -= fabsf(am[m]);

  float n2 = 0.0f;
  #pragma unroll
  for (int d = 0; d < 6; d++) n2 = fmaf(dV[d], dV[d], n2);
  float r = fmaxf(sc, 0.0f) * rcp_f(n2);

  #pragma unroll
  for (int d = 0; d < 6; d++)
    out[(long)i*6 + d] = f[d] - dV[d]*r + gU[d];
}

extern "C" void kernel_launch(void* const* d_in, const int* in_sizes, int n_in,
                              void* d_out, int out_size, void* d_ws, size_t ws_size,
                              hipStream_t stream)
{
  const float* X    = (const float*)d_in[0];
  const float* U    = (const float*)d_in[1];
  const float* xref = (const float*)d_in[2];
  const float* fw1  = (const float*)d_in[3];
  const float* fb1  = (const float*)d_in[4];
  const float* fw2  = (const float*)d_in[5];
  const float* fb2  = (const float*)d_in[6];
  const float* fw3  = (const float*)d_in[7];
  const float* fb3  = (const float*)d_in[8];
  const float* gw   = (const float*)d_in[9];
  const float* gb   = (const float*)d_in[10];
  const float* iw1  = (const float*)d_in[11];
  const float* ib1  = (const float*)d_in[12];
  const float* iw2  = (const float*)d_in[13];
  const float* ib2  = (const float*)d_in[14];
  const float* iw3  = (const float*)d_in[15];
  const float* ib3  = (const float*)d_in[16];
  const float* iw4  = (const float*)d_in[17];
  const float* ib4  = (const float*)d_in[18];
  const float* im2  = (const float*)d_in[19];
  const float* im3  = (const float*)d_in[20];
  const float* im4  = (const float*)d_in[21];

  float* ws  = (float*)d_ws;
  float* out = (float*)d_out;
  int N = in_sizes[0] / 6;

  holo_yref<<<1, 64, 0, stream>>>(xref, iw1, ib1, iw2, ib2, iw3, ib3,
                                  iw4, ib4, im2, im3, im4, ws);
  int threads = 256;
  int blocks  = (N + threads - 1) / threads;
  holo_main<<<blocks, threads, 0, stream>>>(X, U, xref,
      fw1, fb1, fw2, fb2, fw3, fb3, gw, gb,
      iw1, ib1, iw2, ib2, iw3, ib3, iw4, ib4, im2, im3, im4,
      ws, out, N);
}

// Round 3
// 243.287 us; speedup vs baseline: 4.3975x; 4.3975x over previous
//
#include <hip/hip_runtime.h>

#define EPS 1e-05f
#define ALPHA 0.05f

typedef _Float16 h2v __attribute__((ext_vector_type(2)));

__device__ __forceinline__ float rcp_f(float x){ return __builtin_amdgcn_rcpf(x); }
__device__ __forceinline__ float dot2(h2v a, h2v b, float c){
  return __builtin_amdgcn_fdot2(a, b, c, false);
}

#define LOG2E 1.4426950408889634f
#define LN2   0.6931471805599453f

__device__ __forceinline__ float fast_tanh(float x){
  float ax = fabsf(x);
  float e  = exp2f(ax * (-2.0f * LOG2E));
  float t  = (1.0f - e) * rcp_f(1.0f + e);
  return copysignf(t, x);
}
__device__ __forceinline__ float fast_sp(float x){
  float ax = fabsf(x);
  float e  = exp2f(ax * -LOG2E);
  return fmaxf(x, 0.0f) + log2f(1.0f + e) * LN2;
}
__device__ __forceinline__ float fast_sig(float x){
  float ax = fabsf(x);
  float e  = exp2f(ax * -LOG2E);
  float r  = rcp_f(1.0f + e);
  return x >= 0.0f ? r : e * r;
}
__device__ __forceinline__ float sig_from_sp(float sp){
  return 1.0f - exp2f(sp * -LOG2E);
}
__device__ __forceinline__ h2v mkh2(float a, float b){
  h2v r; r.x = (_Float16)a; r.y = (_Float16)b; return r;
}

// ================= fused kernel: stage + pack + yref + compute =================
__global__ __launch_bounds__(512, 4) void holo_main(
    const float* __restrict__ X, const float* __restrict__ U,
    const float* __restrict__ xref,
    const float* __restrict__ fw1, const float* __restrict__ fb1,
    const float* __restrict__ fw2, const float* __restrict__ fb2,
    const float* __restrict__ fw3, const float* __restrict__ fb3,
    const float* __restrict__ gw,  const float* __restrict__ gb,
    const float* __restrict__ iw1, const float* __restrict__ ib1,
    const float* __restrict__ iw2, const float* __restrict__ ib2,
    const float* __restrict__ iw3, const float* __restrict__ ib3,
    const float* __restrict__ iw4, const float* __restrict__ ib4,
    const float* __restrict__ im2, const float* __restrict__ im3,
    const float* __restrict__ im4,
    float* __restrict__ out, int N)
{
  // ---- LDS: all weights, f16-packed (61,008 B) + f32 smalls (2,664 B) ----
  __shared__ h2v sW2[8000];    // fw2 [200][40 pairs over k]
  __shared__ h2v sW3[600];     // fw3 [6][100 pairs over j]
  __shared__ h2v sPW1[240];    // fw1 [80][3]
  __shared__ h2v sPG[108];     // gw  [36][3]
  __shared__ h2v sPI1[180];    // iw1 [60][3]
  __shared__ h2v sPI1C[180];   // iw1^T pairs: [30 k1-pairs][6]
  __shared__ h2v sPI3[900];    // iw3 [30][30 j-pairs]
  __shared__ h2v sPI3C[900];   // iw3^T pairs: [60 j][15 i3-pairs]
  __shared__ h2v sPM2[180];    // im2 [60][3]
  __shared__ h2v sPM2C[180];   // im2^T pairs: [30 j-pairs][6]
  __shared__ h2v sPM3[90];     // im3 [30][3]
  __shared__ h2v sPM3C[90];    // im3^T pairs: [15 i3-pairs][6]
  __shared__ h2v sPM4[4];      // im4 [3]
  __shared__ h2v sPI2T[1800];  // iw2 transposed stream: [30 k1-pairs][60 j]
  __shared__ h2v sPI2C[1800];  // iw2 col pairs: [60 k1][30 j-pairs]
  __shared__ float sFB1[80], sFB2[200], sFB3[6], sGB[36];
  __shared__ float sIB1[60], sIB2[60], sIB3[30], sIW4[30], sIM4[6], sXREF[6];
  __shared__ float sS1[60], sS2[60], sS3[30];
  __shared__ float sYREF, sIB4;

  const int t = threadIdx.x;
  const int T = 512;

  // ---- stage + pack from original weights ----
  for (int i=t;i<8000;i+=T){ int j=i/40,p=i%40; sW2[i]=mkh2(fw2[j*80+2*p],fw2[j*80+2*p+1]); }
  for (int i=t;i<600;i+=T){ int d=i/100,q=i%100; sW3[i]=mkh2(fw3[d*200+2*q],fw3[d*200+2*q+1]); }
  for (int i=t;i<240;i+=T){ int o=i/3,p=i%3; sPW1[i]=mkh2(fw1[o*6+2*p],fw1[o*6+2*p+1]); }
  for (int i=t;i<108;i+=T){ int o=i/3,p=i%3; sPG[i]=mkh2(gw[o*6+2*p],gw[o*6+2*p+1]); }
  for (int i=t;i<180;i+=T){ int o=i/3,p=i%3; sPI1[i]=mkh2(iw1[o*6+2*p],iw1[o*6+2*p+1]); }
  for (int i=t;i<180;i+=T){ int q=i/6,d=i%6; sPI1C[i]=mkh2(iw1[(2*q)*6+d],iw1[(2*q+1)*6+d]); }
  for (int i=t;i<900;i+=T){ int r=i/30,q=i%30; sPI3[i]=mkh2(iw3[r*60+2*q],iw3[r*60+2*q+1]); }
  for (int i=t;i<900;i+=T){ int j=i/15,q=i%15; sPI3C[i]=mkh2(iw3[(2*q)*60+j],iw3[(2*q+1)*60+j]); }
  for (int i=t;i<180;i+=T){ int j=i/3,p=i%3; sPM2[i]=mkh2(im2[j*6+2*p],im2[j*6+2*p+1]); }
  for (int i=t;i<180;i+=T){ int q=i/6,d=i%6; sPM2C[i]=mkh2(im2[(2*q)*6+d],im2[(2*q+1)*6+d]); }
  for (int i=t;i<90;i+=T){ int r=i/3,p=i%3; sPM3[i]=mkh2(im3[r*6+2*p],im3[r*6+2*p+1]); }
  for (int i=t;i<90;i+=T){ int q=i/6,d=i%6; sPM3C[i]=mkh2(im3[(2*q)*6+d],im3[(2*q+1)*6+d]); }
  for (int i=t;i<3;i+=T) sPM4[i]=mkh2(im4[2*i],im4[2*i+1]);
  for (int i=t;i<1800;i+=T){ int p=i/60,j=i%60; sPI2T[i]=mkh2(iw2[j*60+2*p],iw2[j*60+2*p+1]); }
  for (int i=t;i<1800;i+=T){ int k1=i/30,q=i%30; sPI2C[i]=mkh2(iw2[(2*q)*60+k1],iw2[(2*q+1)*60+k1]); }
  for (int k=t;k<80;k+=T) sFB1[k]=fb1[k];
  for (int k=t;k<200;k+=T) sFB2[k]=fb2[k];
  for (int k=t;k<6;k+=T){ sFB3[k]=fb3[k]; sIM4[k]=im4[k]; sXREF[k]=xref[k]; }
  for (int k=t;k<36;k+=T) sGB[k]=gb[k];
  for (int k=t;k<60;k+=T){ sIB1[k]=ib1[k]; sIB2[k]=ib2[k]; }
  for (int k=t;k<30;k+=T){ sIB3[k]=ib3[k]; sIW4[k]=iw4[k]; }
  if (t==0) sIB4=ib4[0];
  __syncthreads();

  // ---- cooperative yref = icnn(xref) using the SAME staged f16 weights ----
  {
    h2v xrp[3];
    #pragma unroll
    for (int p = 0; p < 3; p++) xrp[p] = mkh2(sXREF[2*p], sXREF[2*p+1]);
    if (t < 60){
      float z = sIB1[t];
      #pragma unroll
      for (int p = 0; p < 3; p++) z = dot2(sPI1[t*3+p], xrp[p], z);
      sS1[t] = fast_sp(z);
    }
    __syncthreads();
    if (t < 60){
      float z = sIB2[t];
      #pragma unroll
      for (int p = 0; p < 3; p++) z = dot2(sPM2[t*3+p], xrp[p], z);
      for (int p = 0; p < 30; p++)
        z = dot2(sPI2T[p*60+t], mkh2(sS1[2*p], sS1[2*p+1]), z);
      sS2[t] = fast_sp(z);
    }
    __syncthreads();
    if (t < 30){
      float z = sIB3[t];
      #pragma unroll
      for (int p = 0; p < 3; p++) z = dot2(sPM3[t*3+p], xrp[p], z);
      for (int q = 0; q < 30; q++)
        z = dot2(sPI3[t*30+q], mkh2(sS2[2*q], sS2[2*q+1]), z);
      sS3[t] = fast_sp(z);
    }
    __syncthreads();
    if (t == 0){
      float y = sIB4;
      #pragma unroll
      for (int p = 0; p < 3; p++) y = dot2(sPM4[p], xrp[p], y);
      for (int j = 0; j < 30; j++) y = fmaf(sIW4[j], sS3[j], y);
      sYREF = y;
    }
    __syncthreads();
  }

  // ---- per-thread sample compute ----
  const int i = blockIdx.x * blockDim.x + t;
  if (i < N) {
    float x[6]; h2v xp[3];
    #pragma unroll
    for (int k = 0; k < 6; k++) x[k] = X[(long)i*6 + k];
    #pragma unroll
    for (int p = 0; p < 3; p++) xp[p] = mkh2(x[2*p], x[2*p+1]);

    // ============ FNN layer 1: 6 -> 80, tanh ============
    h2v h1p[40];
    #pragma unroll
    for (int o = 0; o < 80; o += 2){
      float z0 = sFB1[o], z1 = sFB1[o+1];
      #pragma unroll
      for (int p = 0; p < 3; p++){
        z0 = dot2(sPW1[o*3 + p],     xp[p], z0);
        z1 = dot2(sPW1[(o+1)*3 + p], xp[p], z1);
      }
      h1p[o/2] = mkh2(fast_tanh(z0), fast_tanh(z1));
    }

    // ============ FNN layers 2+3 fused: 80 -> 200 -> 6 ============
    float f[6];
    #pragma unroll
    for (int d = 0; d < 6; d++) f[d] = sFB3[d];
    for (int j = 0; j < 200; j += 2){
      float z0 = sFB2[j], z1 = sFB2[j+1];
      #pragma unroll
      for (int p = 0; p < 40; p++){
        h2v hp = h1p[p];
        z0 = dot2(sW2[(j+0)*40 + p], hp, z0);
        z1 = dot2(sW2[(j+1)*40 + p], hp, z1);
      }
      h2v tp = mkh2(fast_tanh(z0), fast_tanh(z1));
      #pragma unroll
      for (int d = 0; d < 6; d++) f[d] = dot2(sW3[d*100 + (j>>1)], tp, f[d]);
    }

    // ============ ICNN forward ============
    float c2[60];
    #pragma unroll
    for (int j = 0; j < 60; j++){
      float z = sIB2[j];
      #pragma unroll
      for (int p = 0; p < 3; p++) z = dot2(sPM2[j*3 + p], xp[p], z);
      c2[j] = z;
    }
    for (int p = 0; p < 30; p++){           // k1 pairs, streamed
      float za = sIB1[2*p], zb = sIB1[2*p+1];
      #pragma unroll
      for (int q = 0; q < 3; q++){
        za = dot2(sPI1[(2*p)*3 + q],   xp[q], za);
        zb = dot2(sPI1[(2*p+1)*3 + q], xp[q], zb);
      }
      h2v s = mkh2(fast_sp(za), fast_sp(zb));
      #pragma unroll
      for (int j = 0; j < 60; j++) c2[j] = dot2(sPI2T[p*60 + j], s, c2[j]);
    }
    h2v c2p[30];
    #pragma unroll
    for (int j = 0; j < 60; j += 2)
      c2p[j/2] = mkh2(fast_sp(c2[j]), fast_sp(c2[j+1]));

    // layer 3 fwd + y + g3
    float y = sIB4;
    #pragma unroll
    for (int p = 0; p < 3; p++) y = dot2(sPM4[p], xp[p], y);
    float ac[6];
    #pragma unroll
    for (int d = 0; d < 6; d++) ac[d] = sIM4[d];
    float g3[30];
    #pragma unroll
    for (int i3 = 0; i3 < 30; i3++){
      float z = sIB3[i3];
      #pragma unroll
      for (int p = 0; p < 3; p++) z = dot2(sPM3[i3*3 + p], xp[p], z);
      #pragma unroll
      for (int q = 0; q < 30; q++) z = dot2(sPI3[i3*30 + q], c2p[q], z);
      float sp3 = fast_sp(z);
      float w4  = sIW4[i3];
      y = fmaf(w4, sp3, y);
      g3[i3] = w4 * sig_from_sp(sp3);
    }
    h2v g3p[15];
    #pragma unroll
    for (int q = 0; q < 15; q++) g3p[q] = mkh2(g3[2*q], g3[2*q+1]);
    #pragma unroll
    for (int q = 0; q < 15; q++){
      #pragma unroll
      for (int d = 0; d < 6; d++) ac[d] = dot2(sPM3C[q*6 + d], g3p[q], ac[d]);
    }

    // bwd g2
    h2v g2p[30];
    #pragma unroll
    for (int j = 0; j < 60; j += 2){
      float ta = 0.0f, tb = 0.0f;
      #pragma unroll
      for (int q = 0; q < 15; q++){
        ta = dot2(sPI3C[j*15 + q],     g3p[q], ta);
        tb = dot2(sPI3C[(j+1)*15 + q], g3p[q], tb);
      }
      h2v sp = c2p[j/2];
      ta *= sig_from_sp((float)sp.x);
      tb *= sig_from_sp((float)sp.y);
      h2v tp = mkh2(ta, tb);
      g2p[j/2] = tp;
      #pragma unroll
      for (int d = 0; d < 6; d++) ac[d] = dot2(sPM2C[(j/2)*6 + d], tp, ac[d]);
    }

    // bwd g1 (streamed; z1 recomputed)
    for (int p = 0; p < 30; p++){
      float za = sIB1[2*p], zb = sIB1[2*p+1];
      #pragma unroll
      for (int q = 0; q < 3; q++){
        za = dot2(sPI1[(2*p)*3 + q],   xp[q], za);
        zb = dot2(sPI1[(2*p+1)*3 + q], xp[q], zb);
      }
      float ta = 0.0f, tb = 0.0f;
      #pragma unroll
      for (int q = 0; q < 30; q++){
        ta = dot2(sPI2C[(2*p)*30 + q],   g2p[q], ta);
        tb = dot2(sPI2C[(2*p+1)*30 + q], g2p[q], tb);
      }
      ta *= fast_sig(za); tb *= fast_sig(zb);
      h2v tp = mkh2(ta, tb);
      #pragma unroll
      for (int d = 0; d < 6; d++) ac[d] = dot2(sPI1C[p*6 + d], tp, ac[d]);
    }

    // ============ V, dV ============
    float h = y - sYREF;
    float sigma = (h >= 1.0f) ? (h - 0.5f) : ((h > 0.0f) ? 0.5f*h*h : 0.0f);
    float sigp  = (h >= 1.0f) ? 1.0f       : ((h > 0.0f) ? h        : 0.0f);
    float dx2 = 0.0f;
    float dV[6];
    #pragma unroll
    for (int d = 0; d < 6; d++){
      float dx = x[d] - sXREF[d];
      dx2 = fmaf(dx, dx, dx2);
      dV[d] = fmaf(sigp, ac[d], 2.0f*EPS*dx);
    }
    float V = sigma + EPS*dx2;

    float sc = ALPHA * V;
    #pragma unroll
    for (int d = 0; d < 6; d++) sc = fmaf(dV[d], f[d], sc);

    // ============ GNN + combine ============
    float u[6];
    #pragma unroll
    for (int m = 0; m < 6; m++) u[m] = U[(long)i*6 + m];
    float am[6] = {0.f,0.f,0.f,0.f,0.f,0.f};
    float gU[6];
    #pragma unroll
    for (int d = 0; d < 6; d++){
      float acc = 0.0f;
      #pragma unroll
      for (int m = 0; m < 6; m++){
        int o = d*6 + m;
        float g = sGB[o];
        #pragma unroll
        for (int p = 0; p < 3; p++) g = dot2(sPG[o*3 + p], xp[p], g);
        am[m] = fmaf(dV[d], g, am[m]);
        acc   = fmaf(g, u[m], acc);
      }
      gU[d] = acc;
    }
    #pragma unroll
    for (int m = 0; m < 6; m++) sc -= fabsf(am[m]);

    float n2 = 0.0f;
    #pragma unroll
    for (int d = 0; d < 6; d++) n2 = fmaf(dV[d], dV[d], n2);
    float r = fmaxf(sc, 0.0f) * rcp_f(n2);

    #pragma unroll
    for (int d = 0; d < 6; d++)
      out[(long)i*6 + d] = f[d] - dV[d]*r + gU[d];
  }
}

extern "C" void kernel_launch(void* const* d_in, const int* in_sizes, int n_in,
                              void* d_out, int out_size, void* d_ws, size_t ws_size,
                              hipStream_t stream)
{
  const float* X    = (const float*)d_in[0];
  const float* U    = (const float*)d_in[1];
  const float* xref = (const float*)d_in[2];
  const float* fw1  = (const float*)d_in[3];
  const float* fb1  = (const float*)d_in[4];
  const float* fw2  = (const float*)d_in[5];
  const float* fb2  = (const float*)d_in[6];
  const float* fw3  = (const float*)d_in[7];
  const float* fb3  = (const float*)d_in[8];
  const float* gw   = (const float*)d_in[9];
  const float* gb   = (const float*)d_in[10];
  const float* iw1  = (const float*)d_in[11];
  const float* ib1  = (const float*)d_in[12];
  const float* iw2  = (const float*)d_in[13];
  const float* ib2  = (const float*)d_in[14];
  const float* iw3  = (const float*)d_in[15];
  const float* ib3  = (const float*)d_in[16];
  const float* iw4  = (const float*)d_in[17];
  const float* ib4  = (const float*)d_in[18];
  const float* im2  = (const float*)d_in[19];
  const float* im3  = (const float*)d_in[20];
  const float* im4  = (const float*)d_in[21];

  float* out = (float*)d_out;
  int N = in_sizes[0] / 6;

  int threads = 512;
  int blocks  = (N + threads - 1) / threads;
  holo_main<<<blocks, threads, 0, stream>>>(X, U, xref,
      fw1, fb1, fw2, fb2, fw3, fb3, gw, gb,
      iw1, ib1, iw2, ib2, iw3, ib3, iw4, ib4, im2, im3, im4,
      out, N);
}

// Round 4
// 238.231 us; speedup vs baseline: 4.4908x; 1.0212x over previous
//
#include <hip/hip_runtime.h>

#define EPS 1e-05f
#define ALPHA 0.05f

typedef _Float16 h2v __attribute__((ext_vector_type(2)));

__device__ __forceinline__ float rcp_f(float x){ return __builtin_amdgcn_rcpf(x); }
__device__ __forceinline__ float dot2(h2v a, h2v b, float c){
  return __builtin_amdgcn_fdot2(a, b, c, false);
}

#define LOG2E 1.4426950408889634f
#define LN2   0.6931471805599453f

__device__ __forceinline__ float fast_tanh(float x){
  float ax = fabsf(x);
  float e  = exp2f(ax * (-2.0f * LOG2E));
  float t  = (1.0f - e) * rcp_f(1.0f + e);
  return copysignf(t, x);
}
__device__ __forceinline__ float fast_sp(float x){
  float ax = fabsf(x);
  float e  = exp2f(ax * -LOG2E);
  return fmaxf(x, 0.0f) + log2f(1.0f + e) * LN2;
}
__device__ __forceinline__ float fast_sig(float x){
  float ax = fabsf(x);
  float e  = exp2f(ax * -LOG2E);
  float r  = rcp_f(1.0f + e);
  return x >= 0.0f ? r : e * r;
}
__device__ __forceinline__ float sig_from_sp(float sp){
  return 1.0f - exp2f(sp * -LOG2E);
}
__device__ __forceinline__ h2v mkh2(float a, float b){
  h2v r; r.x = (_Float16)a; r.y = (_Float16)b; return r;
}

// ================= fused kernel: stage + pack + yref + compute =================
// __launch_bounds__(512, 2): this toolchain treats arg2 as min BLOCKS/CU
// (CUDA semantics). 2 blocks/CU matches the LDS cap (64 KB/block of 160 KB)
// and allows 128 VGPRs; (512,4) forced 64 VGPRs -> ~97 MB of scratch spills.
__global__ __launch_bounds__(512, 2) void holo_main(
    const float* __restrict__ X, const float* __restrict__ U,
    const float* __restrict__ xref,
    const float* __restrict__ fw1, const float* __restrict__ fb1,
    const float* __restrict__ fw2, const float* __restrict__ fb2,
    const float* __restrict__ fw3, const float* __restrict__ fb3,
    const float* __restrict__ gw,  const float* __restrict__ gb,
    const float* __restrict__ iw1, const float* __restrict__ ib1,
    const float* __restrict__ iw2, const float* __restrict__ ib2,
    const float* __restrict__ iw3, const float* __restrict__ ib3,
    const float* __restrict__ iw4, const float* __restrict__ ib4,
    const float* __restrict__ im2, const float* __restrict__ im3,
    const float* __restrict__ im4,
    float* __restrict__ out, int N)
{
  // ---- LDS: all weights, f16-packed (61,008 B) + f32 smalls (2,664 B) ----
  __shared__ h2v sW2[8000];    // fw2 [200][40 pairs over k]
  __shared__ h2v sW3[600];     // fw3 [6][100 pairs over j]
  __shared__ h2v sPW1[240];    // fw1 [80][3]
  __shared__ h2v sPG[108];     // gw  [36][3]
  __shared__ h2v sPI1[180];    // iw1 [60][3]
  __shared__ h2v sPI1C[180];   // iw1^T pairs: [30 k1-pairs][6]
  __shared__ h2v sPI3[900];    // iw3 [30][30 j-pairs]
  __shared__ h2v sPI3C[900];   // iw3^T pairs: [60 j][15 i3-pairs]
  __shared__ h2v sPM2[180];    // im2 [60][3]
  __shared__ h2v sPM2C[180];   // im2^T pairs: [30 j-pairs][6]
  __shared__ h2v sPM3[90];     // im3 [30][3]
  __shared__ h2v sPM3C[90];    // im3^T pairs: [15 i3-pairs][6]
  __shared__ h2v sPM4[4];      // im4 [3]
  __shared__ h2v sPI2T[1800];  // iw2 transposed stream: [30 k1-pairs][60 j]
  __shared__ h2v sPI2C[1800];  // iw2 col pairs: [60 k1][30 j-pairs]
  __shared__ float sFB1[80], sFB2[200], sFB3[6], sGB[36];
  __shared__ float sIB1[60], sIB2[60], sIB3[30], sIW4[30], sIM4[6], sXREF[6];
  __shared__ float sS1[60], sS2[60], sS3[30];
  __shared__ float sYREF, sIB4;

  const int t = threadIdx.x;
  const int T = 512;

  // ---- stage + pack from original weights ----
  for (int i=t;i<8000;i+=T){ int j=i/40,p=i%40; sW2[i]=mkh2(fw2[j*80+2*p],fw2[j*80+2*p+1]); }
  for (int i=t;i<600;i+=T){ int d=i/100,q=i%100; sW3[i]=mkh2(fw3[d*200+2*q],fw3[d*200+2*q+1]); }
  for (int i=t;i<240;i+=T){ int o=i/3,p=i%3; sPW1[i]=mkh2(fw1[o*6+2*p],fw1[o*6+2*p+1]); }
  for (int i=t;i<108;i+=T){ int o=i/3,p=i%3; sPG[i]=mkh2(gw[o*6+2*p],gw[o*6+2*p+1]); }
  for (int i=t;i<180;i+=T){ int o=i/3,p=i%3; sPI1[i]=mkh2(iw1[o*6+2*p],iw1[o*6+2*p+1]); }
  for (int i=t;i<180;i+=T){ int q=i/6,d=i%6; sPI1C[i]=mkh2(iw1[(2*q)*6+d],iw1[(2*q+1)*6+d]); }
  for (int i=t;i<900;i+=T){ int r=i/30,q=i%30; sPI3[i]=mkh2(iw3[r*60+2*q],iw3[r*60+2*q+1]); }
  for (int i=t;i<900;i+=T){ int j=i/15,q=i%15; sPI3C[i]=mkh2(iw3[(2*q)*60+j],iw3[(2*q+1)*60+j]); }
  for (int i=t;i<180;i+=T){ int j=i/3,p=i%3; sPM2[i]=mkh2(im2[j*6+2*p],im2[j*6+2*p+1]); }
  for (int i=t;i<180;i+=T){ int q=i/6,d=i%6; sPM2C[i]=mkh2(im2[(2*q)*6+d],im2[(2*q+1)*6+d]); }
  for (int i=t;i<90;i+=T){ int r=i/3,p=i%3; sPM3[i]=mkh2(im3[r*6+2*p],im3[r*6+2*p+1]); }
  for (int i=t;i<90;i+=T){ int q=i/6,d=i%6; sPM3C[i]=mkh2(im3[(2*q)*6+d],im3[(2*q+1)*6+d]); }
  for (int i=t;i<3;i+=T) sPM4[i]=mkh2(im4[2*i],im4[2*i+1]);
  for (int i=t;i<1800;i+=T){ int p=i/60,j=i%60; sPI2T[i]=mkh2(iw2[j*60+2*p],iw2[j*60+2*p+1]); }
  for (int i=t;i<1800;i+=T){ int k1=i/30,q=i%30; sPI2C[i]=mkh2(iw2[(2*q)*60+k1],iw2[(2*q+1)*60+k1]); }
  for (int k=t;k<80;k+=T) sFB1[k]=fb1[k];
  for (int k=t;k<200;k+=T) sFB2[k]=fb2[k];
  for (int k=t;k<6;k+=T){ sFB3[k]=fb3[k]; sIM4[k]=im4[k]; sXREF[k]=xref[k]; }
  for (int k=t;k<36;k+=T) sGB[k]=gb[k];
  for (int k=t;k<60;k+=T){ sIB1[k]=ib1[k]; sIB2[k]=ib2[k]; }
  for (int k=t;k<30;k+=T){ sIB3[k]=ib3[k]; sIW4[k]=iw4[k]; }
  if (t==0) sIB4=ib4[0];
  __syncthreads();

  // ---- cooperative yref = icnn(xref) using the SAME staged f16 weights ----
  {
    h2v xrp[3];
    #pragma unroll
    for (int p = 0; p < 3; p++) xrp[p] = mkh2(sXREF[2*p], sXREF[2*p+1]);
    if (t < 60){
      float z = sIB1[t];
      #pragma unroll
      for (int p = 0; p < 3; p++) z = dot2(sPI1[t*3+p], xrp[p], z);
      sS1[t] = fast_sp(z);
    }
    __syncthreads();
    if (t < 60){
      float z = sIB2[t];
      #pragma unroll
      for (int p = 0; p < 3; p++) z = dot2(sPM2[t*3+p], xrp[p], z);
      for (int p = 0; p < 30; p++)
        z = dot2(sPI2T[p*60+t], mkh2(sS1[2*p], sS1[2*p+1]), z);
      sS2[t] = fast_sp(z);
    }
    __syncthreads();
    if (t < 30){
      float z = sIB3[t];
      #pragma unroll
      for (int p = 0; p < 3; p++) z = dot2(sPM3[t*3+p], xrp[p], z);
      for (int q = 0; q < 30; q++)
        z = dot2(sPI3[t*30+q], mkh2(sS2[2*q], sS2[2*q+1]), z);
      sS3[t] = fast_sp(z);
    }
    __syncthreads();
    if (t == 0){
      float y = sIB4;
      #pragma unroll
      for (int p = 0; p < 3; p++) y = dot2(sPM4[p], xrp[p], y);
      for (int j = 0; j < 30; j++) y = fmaf(sIW4[j], sS3[j], y);
      sYREF = y;
    }
    __syncthreads();
  }

  // ---- per-thread sample compute ----
  const int i = blockIdx.x * blockDim.x + t;
  if (i < N) {
    float x[6]; h2v xp[3];
    #pragma unroll
    for (int k = 0; k < 6; k++) x[k] = X[(long)i*6 + k];
    #pragma unroll
    for (int p = 0; p < 3; p++) xp[p] = mkh2(x[2*p], x[2*p+1]);

    // ============ FNN layer 1: 6 -> 80, tanh ============
    h2v h1p[40];
    #pragma unroll
    for (int o = 0; o < 80; o += 2){
      float z0 = sFB1[o], z1 = sFB1[o+1];
      #pragma unroll
      for (int p = 0; p < 3; p++){
        z0 = dot2(sPW1[o*3 + p],     xp[p], z0);
        z1 = dot2(sPW1[(o+1)*3 + p], xp[p], z1);
      }
      h1p[o/2] = mkh2(fast_tanh(z0), fast_tanh(z1));
    }

    // ============ FNN layers 2+3 fused: 80 -> 200 -> 6 ============
    float f[6];
    #pragma unroll
    for (int d = 0; d < 6; d++) f[d] = sFB3[d];
    for (int j = 0; j < 200; j += 2){
      float z0 = sFB2[j], z1 = sFB2[j+1];
      #pragma unroll
      for (int p = 0; p < 40; p++){
        h2v hp = h1p[p];
        z0 = dot2(sW2[(j+0)*40 + p], hp, z0);
        z1 = dot2(sW2[(j+1)*40 + p], hp, z1);
      }
      h2v tp = mkh2(fast_tanh(z0), fast_tanh(z1));
      #pragma unroll
      for (int d = 0; d < 6; d++) f[d] = dot2(sW3[d*100 + (j>>1)], tp, f[d]);
    }

    // ============ ICNN forward ============
    float c2[60];
    #pragma unroll
    for (int j = 0; j < 60; j++){
      float z = sIB2[j];
      #pragma unroll
      for (int p = 0; p < 3; p++) z = dot2(sPM2[j*3 + p], xp[p], z);
      c2[j] = z;
    }
    for (int p = 0; p < 30; p++){           // k1 pairs, streamed
      float za = sIB1[2*p], zb = sIB1[2*p+1];
      #pragma unroll
      for (int q = 0; q < 3; q++){
        za = dot2(sPI1[(2*p)*3 + q],   xp[q], za);
        zb = dot2(sPI1[(2*p+1)*3 + q], xp[q], zb);
      }
      h2v s = mkh2(fast_sp(za), fast_sp(zb));
      #pragma unroll
      for (int j = 0; j < 60; j++) c2[j] = dot2(sPI2T[p*60 + j], s, c2[j]);
    }
    h2v c2p[30];
    #pragma unroll
    for (int j = 0; j < 60; j += 2)
      c2p[j/2] = mkh2(fast_sp(c2[j]), fast_sp(c2[j+1]));

    // layer 3 fwd + y + g3
    float y = sIB4;
    #pragma unroll
    for (int p = 0; p < 3; p++) y = dot2(sPM4[p], xp[p], y);
    float ac[6];
    #pragma unroll
    for (int d = 0; d < 6; d++) ac[d] = sIM4[d];
    float g3[30];
    #pragma unroll
    for (int i3 = 0; i3 < 30; i3++){
      float z = sIB3[i3];
      #pragma unroll
      for (int p = 0; p < 3; p++) z = dot2(sPM3[i3*3 + p], xp[p], z);
      #pragma unroll
      for (int q = 0; q < 30; q++) z = dot2(sPI3[i3*30 + q], c2p[q], z);
      float sp3 = fast_sp(z);
      float w4  = sIW4[i3];
      y = fmaf(w4, sp3, y);
      g3[i3] = w4 * sig_from_sp(sp3);
    }
    h2v g3p[15];
    #pragma unroll
    for (int q = 0; q < 15; q++) g3p[q] = mkh2(g3[2*q], g3[2*q+1]);
    #pragma unroll
    for (int q = 0; q < 15; q++){
      #pragma unroll
      for (int d = 0; d < 6; d++) ac[d] = dot2(sPM3C[q*6 + d], g3p[q], ac[d]);
    }

    // bwd g2
    h2v g2p[30];
    #pragma unroll
    for (int j = 0; j < 60; j += 2){
      float ta = 0.0f, tb = 0.0f;
      #pragma unroll
      for (int q = 0; q < 15; q++){
        ta = dot2(sPI3C[j*15 + q],     g3p[q], ta);
        tb = dot2(sPI3C[(j+1)*15 + q], g3p[q], tb);
      }
      h2v sp = c2p[j/2];
      ta *= sig_from_sp((float)sp.x);
      tb *= sig_from_sp((float)sp.y);
      h2v tp = mkh2(ta, tb);
      g2p[j/2] = tp;
      #pragma unroll
      for (int d = 0; d < 6; d++) ac[d] = dot2(sPM2C[(j/2)*6 + d], tp, ac[d]);
    }

    // bwd g1 (streamed; z1 recomputed)
    for (int p = 0; p < 30; p++){
      float za = sIB1[2*p], zb = sIB1[2*p+1];
      #pragma unroll
      for (int q = 0; q < 3; q++){
        za = dot2(sPI1[(2*p)*3 + q],   xp[q], za);
        zb = dot2(sPI1[(2*p+1)*3 + q], xp[q], zb);
      }
      float ta = 0.0f, tb = 0.0f;
      #pragma unroll
      for (int q = 0; q < 30; q++){
        ta = dot2(sPI2C[(2*p)*30 + q],   g2p[q], ta);
        tb = dot2(sPI2C[(2*p+1)*30 + q], g2p[q], tb);
      }
      ta *= fast_sig(za); tb *= fast_sig(zb);
      h2v tp = mkh2(ta, tb);
      #pragma unroll
      for (int d = 0; d < 6; d++) ac[d] = dot2(sPI1C[p*6 + d], tp, ac[d]);
    }

    // ============ V, dV ============
    float h = y - sYREF;
    float sigma = (h >= 1.0f) ? (h - 0.5f) : ((h > 0.0f) ? 0.5f*h*h : 0.0f);
    float sigp  = (h >= 1.0f) ? 1.0f       : ((h > 0.0f) ? h        : 0.0f);
    float dx2 = 0.0f;
    float dV[6];
    #pragma unroll
    for (int d = 0; d < 6; d++){
      float dx = x[d] - sXREF[d];
      dx2 = fmaf(dx, dx, dx2);
      dV[d] = fmaf(sigp, ac[d], 2.0f*EPS*dx);
    }
    float V = sigma + EPS*dx2;

    float sc = ALPHA * V;
    #pragma unroll
    for (int d = 0; d < 6; d++) sc = fmaf(dV[d], f[d], sc);

    // ============ GNN + combine ============
    float u[6];
    #pragma unroll
    for (int m = 0; m < 6; m++) u[m] = U[(long)i*6 + m];
    float am[6] = {0.f,0.f,0.f,0.f,0.f,0.f};
    float gU[6];
    #pragma unroll
    for (int d = 0; d < 6; d++){
      float acc = 0.0f;
      #pragma unroll
      for (int m = 0; m < 6; m++){
        int o = d*6 + m;
        float g = sGB[o];
        #pragma unroll
        for (int p = 0; p < 3; p++) g = dot2(sPG[o*3 + p], xp[p], g);
        am[m] = fmaf(dV[d], g, am[m]);
        acc   = fmaf(g, u[m], acc);
      }
      gU[d] = acc;
    }
    #pragma unroll
    for (int m = 0; m < 6; m++) sc -= fabsf(am[m]);

    float n2 = 0.0f;
    #pragma unroll
    for (int d = 0; d < 6; d++) n2 = fmaf(dV[d], dV[d], n2);
    float r = fmaxf(sc, 0.0f) * rcp_f(n2);

    #pragma unroll
    for (int d = 0; d < 6; d++)
      out[(long)i*6 + d] = f[d] - dV[d]*r + gU[d];
  }
}

extern "C" void kernel_launch(void* const* d_in, const int* in_sizes, int n_in,
                              void* d_out, int out_size, void* d_ws, size_t ws_size,
                              hipStream_t stream)
{
  const float* X    = (const float*)d_in[0];
  const float* U    = (const float*)d_in[1];
  const float* xref = (const float*)d_in[2];
  const float* fw1  = (const float*)d_in[3];
  const float* fb1  = (const float*)d_in[4];
  const float* fw2  = (const float*)d_in[5];
  const float* fb2  = (const float*)d_in[6];
  const float* fw3  = (const float*)d_in[7];
  const float* fb3  = (const float*)d_in[8];
  const float* gw   = (const float*)d_in[9];
  const float* gb   = (const float*)d_in[10];
  const float* iw1  = (const float*)d_in[11];
  const float* ib1  = (const float*)d_in[12];
  const float* iw2  = (const float*)d_in[13];
  const float* ib2  = (const float*)d_in[14];
  const float* iw3  = (const float*)d_in[15];
  const float* ib3  = (const float*)d_in[16];
  const float* iw4  = (const float*)d_in[17];
  const float* ib4  = (const float*)d_in[18];
  const float* im2  = (const float*)d_in[19];
  const float* im3  = (const float*)d_in[20];
  const float* im4  = (const float*)d_in[21];

  float* out = (float*)d_out;
  int N = in_sizes[0] / 6;

  int threads = 512;
  int blocks  = (N + threads - 1) / threads;
  holo_main<<<blocks, threads, 0, stream>>>(X, U, xref,
      fw1, fb1, fw2, fb2, fw3, fb3, gw, gb,
      iw1, ib1, iw2, ib2, iw3, ib3, iw4, ib4, im2, im3, im4,
      out, N);
}

// Round 5
// 182.826 us; speedup vs baseline: 5.8517x; 1.3030x over previous
//
#include <hip/hip_runtime.h>

#define EPS 1e-05f
#define ALPHA 0.05f

typedef _Float16 h2v __attribute__((ext_vector_type(2)));
typedef _Float16 f16x8 __attribute__((ext_vector_type(8)));
typedef float f32x16 __attribute__((ext_vector_type(16)));

__device__ __forceinline__ float rcp_f(float x){ return __builtin_amdgcn_rcpf(x); }
__device__ __forceinline__ float dot2(h2v a, h2v b, float c){
  return __builtin_amdgcn_fdot2(a, b, c, false);
}

#define LOG2E 1.4426950408889634f
#define LN2   0.6931471805599453f

__device__ __forceinline__ float fast_tanh(float x){
  float ax = fabsf(x);
  float e  = exp2f(ax * (-2.0f * LOG2E));
  float t  = (1.0f - e) * rcp_f(1.0f + e);
  return copysignf(t, x);
}
__device__ __forceinline__ float fast_sp(float x){
  float ax = fabsf(x);
  float e  = exp2f(ax * -LOG2E);
  return fmaxf(x, 0.0f) + log2f(1.0f + e) * LN2;
}
__device__ __forceinline__ float fast_sig(float x){
  float ax = fabsf(x);
  float e  = exp2f(ax * -LOG2E);
  float r  = rcp_f(1.0f + e);
  return x >= 0.0f ? r : e * r;
}
__device__ __forceinline__ float sig_from_sp(float sp){
  return 1.0f - exp2f(sp * -LOG2E);
}
__device__ __forceinline__ h2v mkh2(float a, float b){
  h2v r; r.x = (_Float16)a; r.y = (_Float16)b; return r;
}
__device__ __forceinline__ uint packh(float a, float b){
  ushort lo = __builtin_bit_cast(ushort, (_Float16)a);
  ushort hi = __builtin_bit_cast(ushort, (_Float16)b);
  return (uint)lo | ((uint)hi << 16);
}
__device__ __forceinline__ float f16lo(uint u){
  return (float)__builtin_bit_cast(_Float16, (ushort)(u & 0xffffu));
}
__device__ __forceinline__ float f16hi(uint u){
  return (float)__builtin_bit_cast(_Float16, (ushort)(u >> 16));
}

// ================= fused kernel: stage + pack + yref + compute =================
// launch_bounds(512,2): arg2 = min blocks/CU (CUDA semantics on this toolchain);
// LDS 69.7KB caps at 2 blocks/CU anyway, and this allows 128 VGPRs.
__global__ __launch_bounds__(512, 2) void holo_main(
    const float* __restrict__ X, const float* __restrict__ U,
    const float* __restrict__ xref,
    const float* __restrict__ fw1, const float* __restrict__ fb1,
    const float* __restrict__ fw2, const float* __restrict__ fb2,
    const float* __restrict__ fw3, const float* __restrict__ fb3,
    const float* __restrict__ gw,  const float* __restrict__ gb,
    const float* __restrict__ iw1, const float* __restrict__ ib1,
    const float* __restrict__ iw2, const float* __restrict__ ib2,
    const float* __restrict__ iw3, const float* __restrict__ ib3,
    const float* __restrict__ iw4, const float* __restrict__ ib4,
    const float* __restrict__ im2, const float* __restrict__ im3,
    const float* __restrict__ im4,
    float* __restrict__ out, int N)
{
  // ---- LDS ----
  // W2 row-major f16 [224 rows][84 halves] (rows=neurons, 2 pad halves -> 42-dword
  // stride, gcd(42,32)=2 => 2-way bank aliasing = free; 168B row => 8B aligned)
  __shared__ ushort sW2r[224*84];            // 37,632 B
  // Epilogue table: per neuron n: halves d0..d5 = fw3[d][n], u32[3] = fb2[n] (f32)
  __shared__ uint4  sW3r[224];               //  3,584 B
  __shared__ h2v sPW1[240];    // fw1 [80][3]
  __shared__ h2v sPG[108];     // gw  [36][3]
  __shared__ h2v sPI1[180];    // iw1 [60][3]
  __shared__ h2v sPI1C[180];   // iw1^T pairs: [30 k1-pairs][6]
  __shared__ h2v sPI3[900];    // iw3 [30][30 j-pairs]
  __shared__ h2v sPI3C[900];   // iw3^T pairs: [60 j][15 i3-pairs]
  __shared__ h2v sPM2[180];    // im2 [60][3]
  __shared__ h2v sPM2C[180];   // im2^T pairs: [30 j-pairs][6]
  __shared__ h2v sPM3[90];     // im3 [30][3]
  __shared__ h2v sPM3C[90];    // im3^T pairs: [15 i3-pairs][6]
  __shared__ h2v sPM4[4];      // im4 [3]
  __shared__ h2v sPI2T[1800];  // iw2 transposed stream: [30 k1-pairs][60 j]
  __shared__ h2v sPI2C[1800];  // iw2 col pairs: [60 k1][30 j-pairs]
  __shared__ float sFB1[80], sFB3[6], sGB[36];
  __shared__ float sIB1[60], sIB2[60], sIB3[30], sIW4[30], sIM4[6], sXREF[6];
  __shared__ float sS1[60], sS2[60], sS3[30];
  __shared__ float sYREF, sIB4;

  const int t = threadIdx.x;
  const int T = 512;
  const int lane = t & 63;

  // ---- stage + pack from original weights ----
  for (int idx=t; idx<224*42; idx+=T){          // sW2r as u32 pairs
    int row = idx/42, c = idx%42, k = 2*c;
    uint v = 0;
    if (row < 200 && k < 80) v = packh(fw2[row*80+k], fw2[row*80+k+1]);
    ((uint*)sW2r)[idx] = v;
  }
  for (int n=t; n<224; n+=T){                   // sW3r epilogue table
    uint4 v = {0u,0u,0u,0u};
    if (n < 200){
      v.x = packh(fw3[0*200+n], fw3[1*200+n]);
      v.y = packh(fw3[2*200+n], fw3[3*200+n]);
      v.z = packh(fw3[4*200+n], fw3[5*200+n]);
      v.w = __builtin_bit_cast(uint, fb2[n]);
    }
    sW3r[n] = v;
  }
  for (int i=t;i<240;i+=T){ int o=i/3,p=i%3; sPW1[i]=mkh2(fw1[o*6+2*p],fw1[o*6+2*p+1]); }
  for (int i=t;i<108;i+=T){ int o=i/3,p=i%3; sPG[i]=mkh2(gw[o*6+2*p],gw[o*6+2*p+1]); }
  for (int i=t;i<180;i+=T){ int o=i/3,p=i%3; sPI1[i]=mkh2(iw1[o*6+2*p],iw1[o*6+2*p+1]); }
  for (int i=t;i<180;i+=T){ int q=i/6,d=i%6; sPI1C[i]=mkh2(iw1[(2*q)*6+d],iw1[(2*q+1)*6+d]); }
  for (int i=t;i<900;i+=T){ int r=i/30,q=i%30; sPI3[i]=mkh2(iw3[r*60+2*q],iw3[r*60+2*q+1]); }
  for (int i=t;i<900;i+=T){ int j=i/15,q=i%15; sPI3C[i]=mkh2(iw3[(2*q)*60+j],iw3[(2*q+1)*60+j]); }
  for (int i=t;i<180;i+=T){ int j=i/3,p=i%3; sPM2[i]=mkh2(im2[j*6+2*p],im2[j*6+2*p+1]); }
  for (int i=t;i<180;i+=T){ int q=i/6,d=i%6; sPM2C[i]=mkh2(im2[(2*q)*6+d],im2[(2*q+1)*6+d]); }
  for (int i=t;i<90;i+=T){ int r=i/3,p=i%3; sPM3[i]=mkh2(im3[r*6+2*p],im3[r*6+2*p+1]); }
  for (int i=t;i<90;i+=T){ int q=i/6,d=i%6; sPM3C[i]=mkh2(im3[(2*q)*6+d],im3[(2*q+1)*6+d]); }
  for (int i=t;i<3;i+=T) sPM4[i]=mkh2(im4[2*i],im4[2*i+1]);
  for (int i=t;i<1800;i+=T){ int p=i/60,j=i%60; sPI2T[i]=mkh2(iw2[j*60+2*p],iw2[j*60+2*p+1]); }
  for (int i=t;i<1800;i+=T){ int k1=i/30,q=i%30; sPI2C[i]=mkh2(iw2[(2*q)*60+k1],iw2[(2*q+1)*60+k1]); }
  for (int k=t;k<80;k+=T) sFB1[k]=fb1[k];
  for (int k=t;k<6;k+=T){ sFB3[k]=fb3[k]; sIM4[k]=im4[k]; sXREF[k]=xref[k]; }
  for (int k=t;k<36;k+=T) sGB[k]=gb[k];
  for (int k=t;k<60;k+=T){ sIB1[k]=ib1[k]; sIB2[k]=ib2[k]; }
  for (int k=t;k<30;k+=T){ sIB3[k]=ib3[k]; sIW4[k]=iw4[k]; }
  if (t==0) sIB4=ib4[0];
  __syncthreads();

  // ---- cooperative yref = icnn(xref) using the SAME staged f16 weights ----
  {
    h2v xrp[3];
    #pragma unroll
    for (int p = 0; p < 3; p++) xrp[p] = mkh2(sXREF[2*p], sXREF[2*p+1]);
    if (t < 60){
      float z = sIB1[t];
      #pragma unroll
      for (int p = 0; p < 3; p++) z = dot2(sPI1[t*3+p], xrp[p], z);
      sS1[t] = fast_sp(z);
    }
    __syncthreads();
    if (t < 60){
      float z = sIB2[t];
      #pragma unroll
      for (int p = 0; p < 3; p++) z = dot2(sPM2[t*3+p], xrp[p], z);
      for (int p = 0; p < 30; p++)
        z = dot2(sPI2T[p*60+t], mkh2(sS1[2*p], sS1[2*p+1]), z);
      sS2[t] = fast_sp(z);
    }
    __syncthreads();
    if (t < 30){
      float z = sIB3[t];
      #pragma unroll
      for (int p = 0; p < 3; p++) z = dot2(sPM3[t*3+p], xrp[p], z);
      for (int q = 0; q < 30; q++)
        z = dot2(sPI3[t*30+q], mkh2(sS2[2*q], sS2[2*q+1]), z);
      sS3[t] = fast_sp(z);
    }
    __syncthreads();
    if (t == 0){
      float y = sIB4;
      #pragma unroll
      for (int p = 0; p < 3; p++) y = dot2(sPM4[p], xrp[p], y);
      for (int j = 0; j < 30; j++) y = fmaf(sIW4[j], sS3[j], y);
      sYREF = y;
    }
    __syncthreads();
  }

  // ---- per-thread sample compute (guarded loads/stores, full-wave execution) ----
  const int i = blockIdx.x * blockDim.x + t;
  const bool valid = (i < N);

  float x[6]; h2v xp[3];
  #pragma unroll
  for (int k = 0; k < 6; k++) x[k] = valid ? X[(long)i*6 + k] : 0.0f;
  #pragma unroll
  for (int p = 0; p < 3; p++) xp[p] = mkh2(x[2*p], x[2*p+1]);

  // ============ FNN layer 1: 6 -> 80, tanh (packed u32 pairs) ============
  uint h1u[40];
  #pragma unroll
  for (int o = 0; o < 80; o += 2){
    float z0 = sFB1[o], z1 = sFB1[o+1];
    #pragma unroll
    for (int p = 0; p < 3; p++){
      z0 = dot2(sPW1[o*3 + p],     xp[p], z0);
      z1 = dot2(sPW1[(o+1)*3 + p], xp[p], z1);
    }
    h1u[o/2] = packh(fast_tanh(z0), fast_tanh(z1));
  }

  // ============ FNN L2+L3 via MFMA (32x32x16 f16) ============
  // Per wave: C(200x64) = W2(200x80) . h1^T(80x64); 7 mt x 2 nt x 5 kt MFMAs.
  // A (W2): lane holds A[row = mt*32 + (lane&31)][k = kt*16 + 8*(lane>>5)+e]
  // B (h1): lane holds B[k = kt*16 + 8*(lane>>5)+e][col-sample = nt*32 + (lane&31)]
  // C:      col-sample = lane&31, row-neuron = (reg&3)+8*(reg>>2)+4*(lane>>5)
  const int hh = lane >> 5;
  const int l31 = lane & 31;

  // B-fragments from h1 via ds_bpermute (pull sample (nt*32+l31)'s h1 regs)
  uint bf0[5][4], bf1[5][4];
  {
    int a0 = 4 * l31;          // nt = 0
    int a1 = 4 * (32 + l31);   // nt = 1
    #pragma unroll
    for (int kt = 0; kt < 5; kt++){
      #pragma unroll
      for (int q = 0; q < 4; q++){
        int lo0 = __builtin_amdgcn_ds_bpermute(a0, (int)h1u[kt*8 + q]);
        int hi0 = __builtin_amdgcn_ds_bpermute(a0, (int)h1u[kt*8 + 4 + q]);
        bf0[kt][q] = hh ? (uint)hi0 : (uint)lo0;
        int lo1 = __builtin_amdgcn_ds_bpermute(a1, (int)h1u[kt*8 + q]);
        int hi1 = __builtin_amdgcn_ds_bpermute(a1, (int)h1u[kt*8 + 4 + q]);
        bf1[kt][q] = hh ? (uint)hi1 : (uint)lo1;
      }
    }
  }

  float fp0[6] = {0.f,0.f,0.f,0.f,0.f,0.f};
  float fp1[6] = {0.f,0.f,0.f,0.f,0.f,0.f};
  for (int mt = 0; mt < 7; mt++){
    const int row = mt*32 + l31;
    // A-fragments for all 5 k-tiles (2x ds_read_b64 each, 8B aligned)
    f16x8 af[5];
    #pragma unroll
    for (int kt = 0; kt < 5; kt++){
      const ushort* wp = &sW2r[row*84 + kt*16 + 8*hh];
      uint2 w0 = *(const uint2*)wp;
      uint2 w1 = *(const uint2*)(wp + 4);
      uint4 au; au.x = w0.x; au.y = w0.y; au.z = w1.x; au.w = w1.y;
      af[kt] = __builtin_bit_cast(f16x8, au);
    }
    f32x16 acc0 = {0,0,0,0,0,0,0,0,0,0,0,0,0,0,0,0};
    f32x16 acc1 = {0,0,0,0,0,0,0,0,0,0,0,0,0,0,0,0};
    #pragma unroll
    for (int kt = 0; kt < 5; kt++){
      uint4 b0u; b0u.x=bf0[kt][0]; b0u.y=bf0[kt][1]; b0u.z=bf0[kt][2]; b0u.w=bf0[kt][3];
      uint4 b1u; b1u.x=bf1[kt][0]; b1u.y=bf1[kt][1]; b1u.z=bf1[kt][2]; b1u.w=bf1[kt][3];
      acc0 = __builtin_amdgcn_mfma_f32_32x32x16_f16(af[kt], __builtin_bit_cast(f16x8, b0u), acc0, 0, 0, 0);
      acc1 = __builtin_amdgcn_mfma_f32_32x32x16_f16(af[kt], __builtin_bit_cast(f16x8, b1u), acc1, 0, 0, 0);
    }
    // epilogue: bias + tanh + W3 partial reduction (C layout verified m74/m101)
    #pragma unroll
    for (int reg = 0; reg < 16; reg++){
      int n = mt*32 + (reg & 3) + 8*(reg >> 2) + 4*hh;
      uint4 w = sW3r[n];
      float bias = __builtin_bit_cast(float, w.w);
      float t0 = fast_tanh(acc0[reg] + bias);
      float t1 = fast_tanh(acc1[reg] + bias);
      float w0 = f16lo(w.x), w1 = f16hi(w.x);
      float w2 = f16lo(w.y), w3 = f16hi(w.y);
      float w4 = f16lo(w.z), w5 = f16hi(w.z);
      fp0[0] = fmaf(w0, t0, fp0[0]); fp1[0] = fmaf(w0, t1, fp1[0]);
      fp0[1] = fmaf(w1, t0, fp0[1]); fp1[1] = fmaf(w1, t1, fp1[1]);
      fp0[2] = fmaf(w2, t0, fp0[2]); fp1[2] = fmaf(w2, t1, fp1[2]);
      fp0[3] = fmaf(w3, t0, fp0[3]); fp1[3] = fmaf(w3, t1, fp1[3]);
      fp0[4] = fmaf(w4, t0, fp0[4]); fp1[4] = fmaf(w4, t1, fp1[4]);
      fp0[5] = fmaf(w5, t0, fp0[5]); fp1[5] = fmaf(w5, t1, fp1[5]);
    }
  }
  // merge lane halves (each sample's neuron-sum is split across lane and lane^32),
  // then keep the nt matching this lane's own sample (nt = lane>>5).
  float f[6];
  #pragma unroll
  for (int d = 0; d < 6; d++){
    float s0 = fp0[d] + __shfl_xor(fp0[d], 32, 64);
    float s1 = fp1[d] + __shfl_xor(fp1[d], 32, 64);
    f[d] = sFB3[d] + (hh ? s1 : s0);
  }

  // ============ ICNN forward ============
  float c2[60];
  #pragma unroll
  for (int j = 0; j < 60; j++){
    float z = sIB2[j];
    #pragma unroll
    for (int p = 0; p < 3; p++) z = dot2(sPM2[j*3 + p], xp[p], z);
    c2[j] = z;
  }
  for (int p = 0; p < 30; p++){           // k1 pairs, streamed
    float za = sIB1[2*p], zb = sIB1[2*p+1];
    #pragma unroll
    for (int q = 0; q < 3; q++){
      za = dot2(sPI1[(2*p)*3 + q],   xp[q], za);
      zb = dot2(sPI1[(2*p+1)*3 + q], xp[q], zb);
    }
    h2v s = mkh2(fast_sp(za), fast_sp(zb));
    #pragma unroll
    for (int j = 0; j < 60; j++) c2[j] = dot2(sPI2T[p*60 + j], s, c2[j]);
  }
  h2v c2p[30];
  #pragma unroll
  for (int j = 0; j < 60; j += 2)
    c2p[j/2] = mkh2(fast_sp(c2[j]), fast_sp(c2[j+1]));

  // layer 3 fwd + y + g3
  float y = sIB4;
  #pragma unroll
  for (int p = 0; p < 3; p++) y = dot2(sPM4[p], xp[p], y);
  float ac[6];
  #pragma unroll
  for (int d = 0; d < 6; d++) ac[d] = sIM4[d];
  float g3[30];
  #pragma unroll
  for (int i3 = 0; i3 < 30; i3++){
    float z = sIB3[i3];
    #pragma unroll
    for (int p = 0; p < 3; p++) z = dot2(sPM3[i3*3 + p], xp[p], z);
    #pragma unroll
    for (int q = 0; q < 30; q++) z = dot2(sPI3[i3*30 + q], c2p[q], z);
    float sp3 = fast_sp(z);
    float w4  = sIW4[i3];
    y = fmaf(w4, sp3, y);
    g3[i3] = w4 * sig_from_sp(sp3);
  }
  h2v g3p[15];
  #pragma unroll
  for (int q = 0; q < 15; q++) g3p[q] = mkh2(g3[2*q], g3[2*q+1]);
  #pragma unroll
  for (int q = 0; q < 15; q++){
    #pragma unroll
    for (int d = 0; d < 6; d++) ac[d] = dot2(sPM3C[q*6 + d], g3p[q], ac[d]);
  }

  // bwd g2
  h2v g2p[30];
  #pragma unroll
  for (int j = 0; j < 60; j += 2){
    float ta = 0.0f, tb = 0.0f;
    #pragma unroll
    for (int q = 0; q < 15; q++){
      ta = dot2(sPI3C[j*15 + q],     g3p[q], ta);
      tb = dot2(sPI3C[(j+1)*15 + q], g3p[q], tb);
    }
    h2v sp = c2p[j/2];
    ta *= sig_from_sp((float)sp.x);
    tb *= sig_from_sp((float)sp.y);
    h2v tp = mkh2(ta, tb);
    g2p[j/2] = tp;
    #pragma unroll
    for (int d = 0; d < 6; d++) ac[d] = dot2(sPM2C[(j/2)*6 + d], tp, ac[d]);
  }

  // bwd g1 (streamed; z1 recomputed)
  for (int p = 0; p < 30; p++){
    float za = sIB1[2*p], zb = sIB1[2*p+1];
    #pragma unroll
    for (int q = 0; q < 3; q++){
      za = dot2(sPI1[(2*p)*3 + q],   xp[q], za);
      zb = dot2(sPI1[(2*p+1)*3 + q], xp[q], zb);
    }
    float ta = 0.0f, tb = 0.0f;
    #pragma unroll
    for (int q = 0; q < 30; q++){
      ta = dot2(sPI2C[(2*p)*30 + q],   g2p[q], ta);
      tb = dot2(sPI2C[(2*p+1)*30 + q], g2p[q], tb);
    }
    ta *= fast_sig(za); tb *= fast_sig(zb);
    h2v tp = mkh2(ta, tb);
    #pragma unroll
    for (int d = 0; d < 6; d++) ac[d] = dot2(sPI1C[p*6 + d], tp, ac[d]);
  }

  // ============ V, dV ============
  float hdiff = y - sYREF;
  float sigma = (hdiff >= 1.0f) ? (hdiff - 0.5f) : ((hdiff > 0.0f) ? 0.5f*hdiff*hdiff : 0.0f);
  float sigp  = (hdiff >= 1.0f) ? 1.0f          : ((hdiff > 0.0f) ? hdiff             : 0.0f);
  float dx2 = 0.0f;
  float dV[6];
  #pragma unroll
  for (int d = 0; d < 6; d++){
    float dx = x[d] - sXREF[d];
    dx2 = fmaf(dx, dx, dx2);
    dV[d] = fmaf(sigp, ac[d], 2.0f*EPS*dx);
  }
  float V = sigma + EPS*dx2;

  float sc = ALPHA * V;
  #pragma unroll
  for (int d = 0; d < 6; d++) sc = fmaf(dV[d], f[d], sc);

  // ============ GNN + combine ============
  float u[6];
  #pragma unroll
  for (int m = 0; m < 6; m++) u[m] = valid ? U[(long)i*6 + m] : 0.0f;
  float am[6] = {0.f,0.f,0.f,0.f,0.f,0.f};
  float gU[6];
  #pragma unroll
  for (int d = 0; d < 6; d++){
    float acc = 0.0f;
    #pragma unroll
    for (int m = 0; m < 6; m++){
      int o = d*6 + m;
      float g = sGB[o];
      #pragma unroll
      for (int p = 0; p < 3; p++) g = dot2(sPG[o*3 + p], xp[p], g);
      am[m] = fmaf(dV[d], g, am[m]);
      acc   = fmaf(g, u[m], acc);
    }
    gU[d] = acc;
  }
  #pragma unroll
  for (int m = 0; m < 6; m++) sc -= fabsf(am[m]);

  float n2 = 0.0f;
  #pragma unroll
  for (int d = 0; d < 6; d++) n2 = fmaf(dV[d], dV[d], n2);
  float r = fmaxf(sc, 0.0f) * rcp_f(n2);

  if (valid){
    #pragma unroll
    for (int d = 0; d < 6; d++)
      out[(long)i*6 + d] = f[d] - dV[d]*r + gU[d];
  }
}

extern "C" void kernel_launch(void* const* d_in, const int* in_sizes, int n_in,
                              void* d_out, int out_size, void* d_ws, size_t ws_size,
                              hipStream_t stream)
{
  const float* X    = (const float*)d_in[0];
  const float* U    = (const float*)d_in[1];
  const float* xref = (const float*)d_in[2];
  const float* fw1  = (const float*)d_in[3];
  const float* fb1  = (const float*)d_in[4];
  const float* fw2  = (const float*)d_in[5];
  const float* fb2  = (const float*)d_in[6];
  const float* fw3  = (const float*)d_in[7];
  const float* fb3  = (const float*)d_in[8];
  const float* gw   = (const float*)d_in[9];
  const float* gb   = (const float*)d_in[10];
  const float* iw1  = (const float*)d_in[11];
  const float* ib1  = (const float*)d_in[12];
  const float* iw2  = (const float*)d_in[13];
  const float* ib2  = (const float*)d_in[14];
  const float* iw3  = (const float*)d_in[15];
  const float* ib3  = (const float*)d_in[16];
  const float* iw4  = (const float*)d_in[17];
  const float* ib4  = (const float*)d_in[18];
  const float* im2  = (const float*)d_in[19];
  const float* im3  = (const float*)d_in[20];
  const float* im4  = (const float*)d_in[21];

  float* out = (float*)d_out;
  int N = in_sizes[0] / 6;

  int threads = 512;
  int blocks  = (N + threads - 1) / threads;
  holo_main<<<blocks, threads, 0, stream>>>(X, U, xref,
      fw1, fb1, fw2, fb2, fw3, fb3, gw, gb,
      iw1, ib1, iw2, ib2, iw3, ib3, iw4, ib4, im2, im3, im4,
      out, N);
}